// Round 8
// baseline (109.019 us; speedup 1.0000x reference)
//
#include <hip/hip_runtime.h>
#include <hip/hip_bf16.h>

typedef __attribute__((ext_vector_type(4))) float f32x4;
typedef __attribute__((ext_vector_type(8))) short bf16x8;
typedef __attribute__((ext_vector_type(4))) short bf16x4;
typedef __attribute__((ext_vector_type(2))) unsigned int u32x2;

#define DEV static __device__ __forceinline__

constexpr float LOG2E  = 1.4426950408889634f;
constexpr float QSCALE = 0.17677669529663687f * LOG2E;  // hd^-0.5 * log2e

// ws layout (bytes)
constexpr size_t OFF_Q   = 0;                    // bf16 frag Q  (256 bh x 32 qg x 512)
constexpr size_t OFF_K   = (size_t)8  << 20;     // bf16 frag K  (256 bh x 32 tg x 512)
constexpr size_t OFF_V   = (size_t)16 << 20;     // bf16 frag V  (256 bh x 16 ug x 2 dh x 512), j-permuted
constexpr size_t OFF_RPB = (size_t)24 << 20;     // bf16 frag bias (4 h x 32 qg x 32 jc x 64 lane x 4)
constexpr size_t OFF_AO  = (size_t)27 << 20;     // bf16 head-major (bh, n, 32)
constexpr size_t OFF_POS = (size_t)35 << 20;     // f32  (3375, 4)

DEV short f2b(float f) {
  union { __bf16 h; short s; } u;
  u.h = (__bf16)f;
  return u.s;
}
DEV float b2f(unsigned int u) {
  union { unsigned int u; float f; } x; x.u = u; return x.f;
}
DEV unsigned int pkbf(float a, float b) {
  union { __bf16 h; unsigned short s; } ua, ub;
  ua.h = (__bf16)a; ub.h = (__bf16)b;
  return (unsigned int)ua.s | ((unsigned int)ub.s << 16);
}
// load 8 consecutive f32 weights, scale, convert to a bf16x8 MFMA fragment
DEV bf16x8 w8(const float* __restrict__ p, float s) {
  f32x4 a = *(const f32x4*)p, b = *(const f32x4*)(p + 4);
  bf16x8 r;
  r[0] = f2b(a[0] * s); r[1] = f2b(a[1] * s); r[2] = f2b(a[2] * s); r[3] = f2b(a[3] * s);
  r[4] = f2b(b[0] * s); r[5] = f2b(b[1] * s); r[6] = f2b(b[2] * s); r[7] = f2b(b[3] * s);
  return r;
}

// ---------------- helpers: tiny MLP ----------------
DEV void ln_relu8(const float* v, const float* __restrict__ g,
                  const float* __restrict__ b, float* t) {
  float m = 0.f;
#pragma unroll
  for (int i = 0; i < 8; i++) m += v[i];
  m *= 0.125f;
  float var = 0.f;
#pragma unroll
  for (int i = 0; i < 8; i++) { float d = v[i] - m; var += d * d; }
  var *= 0.125f;
  float inv = 1.0f / sqrtf(var + 1e-5f);
#pragma unroll
  for (int i = 0; i < 8; i++) {
    float u = (v[i] - m) * inv * g[i] + b[i];
    t[i] = u > 0.f ? u : 0.f;
  }
}

DEV void mm8(const float* t, const float* __restrict__ w,
             const float* __restrict__ c, float* o) {
#pragma unroll
  for (int oo = 0; oo < 8; oo++) {
    float a = c[oo];
#pragma unroll
    for (int i = 0; i < 8; i++) a += t[i] * w[oo * 8 + i];
    o[oo] = a;
  }
}

// ---------------- K0: DynamicPosBias MLP (one row per thread) ----------------
__global__ void ca_posmlp(
    const float* __restrict__ pw, const float* __restrict__ pb,
    const float* __restrict__ g1, const float* __restrict__ b1,
    const float* __restrict__ w1, const float* __restrict__ c1,
    const float* __restrict__ g2, const float* __restrict__ b2,
    const float* __restrict__ w2, const float* __restrict__ c2,
    const float* __restrict__ g3, const float* __restrict__ b3,
    const float* __restrict__ w3, const float* __restrict__ c3,
    float* __restrict__ pos_out) {
  int r = blockIdx.x * 256 + threadIdx.x;
  if (r >= 3375) return;
  float x0 = (float)(r / 225 - 7);
  float x1 = (float)((r / 15) % 15 - 7);
  float x2 = (float)(r % 15 - 7);
  float v[8], t[8], u[8];
#pragma unroll
  for (int o = 0; o < 8; o++)
    v[o] = x0 * pw[o * 3] + x1 * pw[o * 3 + 1] + x2 * pw[o * 3 + 2] + pb[o];
  ln_relu8(v, g1, b1, t);
  mm8(t, w1, c1, u);
  ln_relu8(u, g2, b2, t);
  mm8(t, w2, c2, v);
  ln_relu8(v, g3, b3, t);
#pragma unroll
  for (int hh = 0; hh < 4; hh++) {
    float a = c3[hh];
#pragma unroll
    for (int i = 0; i < 8; i++) a += t[i] * w3[hh * 8 + i];
    pos_out[r * 4 + hh] = a * LOG2E;  // log2 domain for exp2-softmax
  }
}

// ---------------- K1: fused QKV projection + rpb frag expand ----------------
// blocks 0..511    : x -> qfrag (on-the-fly f32 weight cvt)
// blocks 512..1023 : y -> kfrag + vfrag (V with PV j-permutation baked in)
// blocks 1024..2047: rpbf expansion (one gid per thread, reads posb from global)
__global__ __launch_bounds__(256) void ca_qkv_rpb(
    const float* __restrict__ x, const float* __restrict__ y,
    const float* __restrict__ qkv_w, const float* __restrict__ qkv_b,
    short* __restrict__ gq, short* __restrict__ gk, short* __restrict__ gv,
    const float* __restrict__ posb, short* __restrict__ rpbf) {
  __shared__ short lds[16384];  // 32KB: input stage (stride 136), then frag relayout
  const int blk = blockIdx.x;
  const int tid = threadIdx.x;

  if (blk >= 1024) {
    // ---- rpb frag expansion: one output gid per thread ----
    int gid = (blk - 1024) * 256 + tid;  // 262144 threads
    int lane = gid & 63, jc = (gid >> 6) & 31, qg = (gid >> 11) & 31, hh = gid >> 16;
    int q = qg * 16 + (lane & 15);
    int j0 = jc * 16 + (lane >> 4) * 4;
    bf16x4 outv;
#pragma unroll
    for (int r = 0; r < 4; r++) {
      int j = j0 + r;
      int rh = (q >> 6) - (j >> 6) + 7;
      int rw = ((q >> 3) & 7) - ((j >> 3) & 7) + 7;
      int rd = (q & 7) - (j & 7) + 7;
      int idx = (rh * 15 + rw) * 15 + rd;
      outv[r] = f2b(posb[idx * 4 + hh]);
    }
    *(bf16x4*)(rpbf + (size_t)gid * 4) = outv;
    return;
  }

  // ---- qkv path ----
  const int z = blk >> 9;          // 0: x->q, 1: y->k+v
  const int t0 = (blk & 511) * 64;
  const int b_ = t0 >> 9;
  const int n0 = t0 & 511;
  const float* __restrict__ in = (z == 0) ? x : y;
  // coalesced input staging: flat f32x4 per thread (64 tokens x 128, stride 136)
#pragma unroll
  for (int i = 0; i < 8; i++) {
    int flat = i * 1024 + tid * 4;
    f32x4 f = *(const f32x4*)(in + (size_t)t0 * 128 + flat);
    int row = flat >> 7, col = flat & 127;
    bf16x4 hv;
#pragma unroll
    for (int e = 0; e < 4; e++) hv[e] = f2b(f[e]);
    *(bf16x4*)(lds + row * 136 + col) = hv;
  }
  __syncthreads();
  const int w = tid >> 6, lane = tid & 63, lr = lane & 15, lg = lane >> 4;
  bf16x8 afrag[4];
  {
    const short* ap = lds + (w * 16 + lr) * 136 + lg * 8;
#pragma unroll
    for (int k4 = 0; k4 < 4; k4++) afrag[k4] = *(const bf16x8*)(ap + k4 * 32);
  }
  __syncthreads();  // all afrag reads done before relayout overwrites lds

  if (z == 0) {
#pragma unroll
    for (int ct = 0; ct < 8; ct++) {
      const int col = ct * 16;
      float bias = qkv_b[col + lr] * QSCALE;
      f32x4 acc = {bias, bias, bias, bias};
      const float* bp = qkv_w + (size_t)(col + lr) * 128 + lg * 8;
#pragma unroll
      for (int k4 = 0; k4 < 4; k4++) {
        bf16x8 bfr = w8(bp + k4 * 32, QSCALE);
        acc = __builtin_amdgcn_mfma_f32_16x16x32_bf16(afrag[k4], bfr, acc, 0, 0, 0);
      }
      const int d = (ct & 1) * 16 + lr;
      const int base = (w * 4 + (ct >> 1)) * 512 + 128 * (d >> 3) + (d & 7);
#pragma unroll
      for (int r = 0; r < 4; r++)
        lds[base + (lg * 4 + r) * 8] = f2b(acc[r]);
    }
  } else {
#pragma unroll
    for (int ct = 0; ct < 16; ct++) {
      const int col = 128 + ct * 16;
      float bias = qkv_b[col + lr];
      f32x4 acc = {bias, bias, bias, bias};
      const float* bp = qkv_w + (size_t)(col + lr) * 128 + lg * 8;
#pragma unroll
      for (int k4 = 0; k4 < 4; k4++) {
        bf16x8 bfr = w8(bp + k4 * 32, 1.0f);
        acc = __builtin_amdgcn_mfma_f32_16x16x32_bf16(afrag[k4], bfr, acc, 0, 0, 0);
      }
      if (ct >= 8) {
        // V frag (PV A-operand-compatible j-permuted layout)
        const int hv_ = (ct - 8) >> 1;
        const int dh = (ct - 8) & 1;
        const int base = 8192 + (((hv_ * 2 + (w >> 1)) * 2 + dh) * 512) + lane * 8 + (w & 1) * 4;
        *(unsigned int*)(lds + base)     = pkbf(acc[0], acc[1]);
        *(unsigned int*)(lds + base + 2) = pkbf(acc[2], acc[3]);
      } else {  // K chunk c = w*4 + (ct>>1)
        const int d = (ct & 1) * 16 + lr;
        const int base = (w * 4 + (ct >> 1)) * 512 + 128 * (d >> 3) + (d & 7);
#pragma unroll
        for (int r = 0; r < 4; r++)
          lds[base + (lg * 4 + r) * 8] = f2b(acc[r]);
      }
    }
  }
  __syncthreads();
  // cooperative 1KB-per-wave coalesced chunk stores
  if (z == 0) {
#pragma unroll
    for (int kk = 0; kk < 4; kk++) {
      const int c = kk * 4 + w, hh = c & 3, tg = c >> 2;
      bf16x8 vd = *(const bf16x8*)(lds + c * 512 + lane * 8);
      *(bf16x8*)(gq + (((size_t)b_ * 4 + hh) * 32 + (n0 >> 4) + tg) * 512 + lane * 8) = vd;
    }
  } else {
#pragma unroll
    for (int kk = 0; kk < 4; kk++) {
      const int c = kk * 4 + w, hh = c & 3, tg = c >> 2;
      bf16x8 vd = *(const bf16x8*)(lds + c * 512 + lane * 8);
      *(bf16x8*)(gk + (((size_t)b_ * 4 + hh) * 32 + (n0 >> 4) + tg) * 512 + lane * 8) = vd;
    }
#pragma unroll
    for (int kk = 0; kk < 4; kk++) {
      const int c = kk * 4 + w, hh = c >> 2, ul = (c >> 1) & 1, dh = c & 1;
      bf16x8 vd = *(const bf16x8*)(lds + 8192 + c * 512 + lane * 8);
      *(bf16x8*)(gv + ((((size_t)b_ * 4 + hh) * 16 + (n0 >> 5) + ul) * 2 + dh) * 512 + lane * 8) = vd;
    }
  }
}

// ---------------- K2: fused attention (dbuf, 4 waves, 1 qg/wave) ----------------
DEV void stage_kv(const short* kg, const short* vg, short* buf, int T, int w, int lane) {
#pragma unroll
  for (int i = 0; i < 4; i++) {
    const int c = w * 4 + i;
    const short* src;
    short* dst;
    if (c < 8) {
      src = kg + ((size_t)(T * 8 + c)) * 512 + lane * 8;
      dst = buf + c * 512;
    } else {
      src = vg + ((size_t)(T * 8 + c - 8)) * 512 + lane * 8;
      dst = buf + 4096 + (c - 8) * 512;
    }
    __builtin_amdgcn_global_load_lds((const __attribute__((address_space(1))) void*)src,
                                     (__attribute__((address_space(3))) void*)dst, 16, 0, 0);
  }
}

__global__ __launch_bounds__(256, 4) void ca_attn(
    const short* __restrict__ qfrag, const short* __restrict__ kfrag,
    const short* __restrict__ vfrag, const short* __restrict__ rpbf,
    short* __restrict__ aob) {
  __shared__ short kv[2][8192];  // dbuf: K tile 8KB | V tile 8KB (per buf 16KB)
  const int bid = blockIdx.x;
  // XCD swizzle: the 8 qt-blocks of one (b,h) share bid%256 -> same XCD slot
  const int qt = bid >> 8, rem = bid & 255;
  const int b_ = rem >> 2, hh = rem & 3;
  const int bh = b_ * 4 + hh;
  const int tid = threadIdx.x;
  const int w = tid >> 6, lane = tid & 63, lg = lane >> 4;
  const int q0 = qt * 64 + w * 16, qg = (q0 >> 4);

  const short* kg = kfrag + (size_t)bh * 16384;
  const short* vg = vfrag + (size_t)bh * 16384;
  const bf16x8 qf = *(const bf16x8*)(qfrag + ((size_t)bh * 32 + qg) * 512 + lane * 8);
  const short* bp = rpbf + ((size_t)(hh * 32 + qg) << 13) + lane * 4;

  union PU { bf16x8 v; unsigned int u[4]; };
  PU ones;
  ones.u[0] = 0x3F803F80u; ones.u[1] = 0x3F803F80u;
  ones.u[2] = 0x3F803F80u; ones.u[3] = 0x3F803F80u;

  stage_kv(kg, vg, &kv[0][0], 0, w, lane);
  __syncthreads();

  f32x4 o0 = {0.f, 0.f, 0.f, 0.f}, o1 = {0.f, 0.f, 0.f, 0.f}, o2 = {0.f, 0.f, 0.f, 0.f};

  for (int T = 0; T < 4; T++) {
    const int cur = T & 1;
    if (T < 3) stage_kv(kg, vg, &kv[cur ^ 1][0], T + 1, w, lane);
    const short* kt = &kv[cur][0];
    const short* vt = &kv[cur][4096];

    u32x2 bw[8];
#pragma unroll
    for (int t = 0; t < 8; t++) bw[t] = *(const u32x2*)(bp + (size_t)(T * 8 + t) * 256);

#pragma unroll
    for (int uu = 0; uu < 4; uu++) {
      PU p;
#pragma unroll
      for (int half = 0; half < 2; half++) {
        const int t = uu * 2 + half;
        bf16x8 kf = *(const bf16x8*)(kt + t * 512 + lane * 8);
        f32x4 cin;
        cin[0] = b2f(bw[t].x << 16);
        cin[1] = b2f(bw[t].x & 0xFFFF0000u);
        cin[2] = b2f(bw[t].y << 16);
        cin[3] = b2f(bw[t].y & 0xFFFF0000u);
        f32x4 s = __builtin_amdgcn_mfma_f32_16x16x32_bf16(kf, qf, cin, 0, 0, 0);
        // no-max softmax: scores bounded (|s| < ~1), exp2 direct is exact-ratio
        p.u[half * 2 + 0] = pkbf(__builtin_exp2f(s[0]), __builtin_exp2f(s[1]));
        p.u[half * 2 + 1] = pkbf(__builtin_exp2f(s[2]), __builtin_exp2f(s[3]));
      }
      bf16x8 vf0 = *(const bf16x8*)(vt + (uu * 2 + 0) * 512 + lane * 8);
      bf16x8 vf1 = *(const bf16x8*)(vt + (uu * 2 + 1) * 512 + lane * 8);
      o0 = __builtin_amdgcn_mfma_f32_16x16x32_bf16(p.v, vf0, o0, 0, 0, 0);
      o1 = __builtin_amdgcn_mfma_f32_16x16x32_bf16(p.v, vf1, o1, 0, 0, 0);
      o2 = __builtin_amdgcn_mfma_f32_16x16x32_bf16(p.v, ones.v, o2, 0, 0, 0);
    }
    if (T < 3) __syncthreads();
  }

  // epilogue: o2[r] = row-sum for q = lg*4+r; normalize + transpose via wave-private LDS
  short* pt = &kv[0][w * 1024];
  const int lr = lane & 15;
#pragma unroll
  for (int r = 0; r < 4; r++) {
    float iv = 1.0f / o2[r];
    pt[(lg * 4 + r) * 40 + lr] = f2b(o0[r] * iv);
    pt[(lg * 4 + r) * 40 + 16 + lr] = f2b(o1[r] * iv);
  }
  asm volatile("s_waitcnt lgkmcnt(0)" ::: "memory");
  __builtin_amdgcn_sched_barrier(0);
  {
    const int qq = lane >> 2, pp = lane & 3;
    bf16x8 od = *(const bf16x8*)(pt + qq * 40 + pp * 8);
    *(bf16x8*)(aob + ((size_t)bh * 512 + q0 + qq) * 32 + pp * 8) = od;  // 1KB/wave coalesced
  }
}

// ---------------- K3: output projection (on-the-fly weight cvt, LDS-transposed stores) ----------------
__global__ __launch_bounds__(256) void ca_proj(
    const short* __restrict__ aob, const float* __restrict__ proj_w,
    const float* __restrict__ proj_b, float* __restrict__ out) {
  __shared__ float plds[8448];  // 4 waves x 16x132 f32
  const int t0 = blockIdx.x * 64;
  const int b_ = t0 >> 9, n0 = t0 & 511;
  const int tid = threadIdx.x;
  const int w = tid >> 6, lane = tid & 63, lr = lane & 15, lg = lane >> 4;
  bf16x8 afrag[4];
#pragma unroll
  for (int k4 = 0; k4 < 4; k4++)
    afrag[k4] = *(const bf16x8*)(aob + (((size_t)b_ * 4 + k4) * 512 + n0 + w * 16 + lr) * 32 + lg * 8);
  float* pt = plds + w * 2112;
#pragma unroll
  for (int ct = 0; ct < 8; ct++) {
    float bias = proj_b[ct * 16 + lr];
    f32x4 acc = {bias, bias, bias, bias};
    const float* bp = proj_w + (size_t)(ct * 16 + lr) * 128 + lg * 8;
#pragma unroll
    for (int k4 = 0; k4 < 4; k4++) {
      bf16x8 bfr = w8(bp + k4 * 32, 1.0f);
      acc = __builtin_amdgcn_mfma_f32_16x16x32_bf16(afrag[k4], bfr, acc, 0, 0, 0);
    }
#pragma unroll
    for (int r = 0; r < 4; r++)
      pt[(lg * 4 + r) * 132 + ct * 16 + lr] = acc[r];
  }
  asm volatile("s_waitcnt lgkmcnt(0)" ::: "memory");
  __builtin_amdgcn_sched_barrier(0);
#pragma unroll
  for (int i = 0; i < 8; i++) {
    int f = i * 256 + lane * 4;
    int row = f >> 7, col = f & 127;
    f32x4 v = *(const f32x4*)(pt + row * 132 + col);
    *(f32x4*)(out + (size_t)(t0 + w * 16) * 128 + f) = v;  // dense 1KB/wave stores
  }
}

extern "C" void kernel_launch(void* const* d_in, const int* in_sizes, int n_in,
                              void* d_out, int out_size, void* d_ws, size_t ws_size,
                              hipStream_t stream) {
  const float* x      = (const float*)d_in[0];
  const float* y      = (const float*)d_in[1];
  const float* qkv_w  = (const float*)d_in[5];
  const float* qkv_b  = (const float*)d_in[6];
  const float* proj_w = (const float*)d_in[7];
  const float* proj_b = (const float*)d_in[8];
  const float* pos_w  = (const float*)d_in[9];
  const float* pos_b  = (const float*)d_in[10];
  const float* ln1g = (const float*)d_in[11];
  const float* ln1b = (const float*)d_in[12];
  const float* p1w  = (const float*)d_in[13];
  const float* p1b  = (const float*)d_in[14];
  const float* ln2g = (const float*)d_in[15];
  const float* ln2b = (const float*)d_in[16];
  const float* p2w  = (const float*)d_in[17];
  const float* p2b  = (const float*)d_in[18];
  const float* ln3g = (const float*)d_in[19];
  const float* ln3b = (const float*)d_in[20];
  const float* p3w  = (const float*)d_in[21];
  const float* p3b  = (const float*)d_in[22];
  float* out = (float*)d_out;

  char* ws = (char*)d_ws;
  short* gq    = (short*)(ws + OFF_Q);
  short* gk    = (short*)(ws + OFF_K);
  short* gv    = (short*)(ws + OFF_V);
  short* rpbf  = (short*)(ws + OFF_RPB);
  short* aob   = (short*)(ws + OFF_AO);
  float* posb  = (float*)(ws + OFF_POS);

  ca_posmlp<<<14, 256, 0, stream>>>(pos_w, pos_b, ln1g, ln1b, p1w, p1b,
                                    ln2g, ln2b, p2w, p2b, ln3g, ln3b, p3w, p3b, posb);
  ca_qkv_rpb<<<2048, 256, 0, stream>>>(x, y, qkv_w, qkv_b, gq, gk, gv, posb, rpbf);
  ca_attn<<<2048, 256, 0, stream>>>(gq, gk, gv, rpbf, aob);
  ca_proj<<<512, 256, 0, stream>>>(aob, proj_w, proj_b, out);
}

// Round 9
// 80.282 us; speedup vs baseline: 1.3579x; 1.3579x over previous
//
#include <hip/hip_runtime.h>
#include <hip/hip_bf16.h>

typedef __attribute__((ext_vector_type(4))) float f32x4;
typedef __attribute__((ext_vector_type(8))) short bf16x8;
typedef __attribute__((ext_vector_type(4))) short bf16x4;
typedef __attribute__((ext_vector_type(2))) unsigned int u32x2;

#define DEV static __device__ __forceinline__

constexpr float LOG2E  = 1.4426950408889634f;
constexpr float QSCALE = 0.17677669529663687f * LOG2E;  // hd^-0.5 * log2e

// ws layout (bytes)
constexpr size_t OFF_Q   = 0;                    // bf16 frag Q  (256 bh x 32 qg x 512)
constexpr size_t OFF_K   = (size_t)8  << 20;     // bf16 frag K  (256 bh x 32 tg x 512)
constexpr size_t OFF_V   = (size_t)16 << 20;     // bf16 frag V  (256 bh x 16 ug x 2 dh x 512), j-permuted
constexpr size_t OFF_RPB = (size_t)24 << 20;     // bf16 frag bias (4 h x 32 qg x 32 jc x 64 lane x 4)
constexpr size_t OFF_AO  = (size_t)27 << 20;     // bf16 head-major (bh, n, 32)
constexpr size_t OFF_POS = (size_t)35 << 20;     // f32  (3375, 4)
constexpr size_t OFF_WQ  = (size_t)36 << 20;     // bf16 (384, 128)
constexpr size_t OFF_WP  = (size_t)37 << 20;     // bf16 (128, 128)

DEV short f2b(float f) {
  union { __bf16 h; short s; } u;
  u.h = (__bf16)f;
  return u.s;
}
DEV float b2f(unsigned int u) {
  union { unsigned int u; float f; } x; x.u = u; return x.f;
}
DEV unsigned int pkbf(float a, float b) {
  union { __bf16 h; unsigned short s; } ua, ub;
  ua.h = (__bf16)a; ub.h = (__bf16)b;
  return (unsigned int)ua.s | ((unsigned int)ub.s << 16);
}

// ---------------- helpers: tiny MLP ----------------
DEV void ln_relu8(const float* v, const float* __restrict__ g,
                  const float* __restrict__ b, float* t) {
  float m = 0.f;
#pragma unroll
  for (int i = 0; i < 8; i++) m += v[i];
  m *= 0.125f;
  float var = 0.f;
#pragma unroll
  for (int i = 0; i < 8; i++) { float d = v[i] - m; var += d * d; }
  var *= 0.125f;
  float inv = 1.0f / sqrtf(var + 1e-5f);
#pragma unroll
  for (int i = 0; i < 8; i++) {
    float u = (v[i] - m) * inv * g[i] + b[i];
    t[i] = u > 0.f ? u : 0.f;
  }
}

DEV void mm8(const float* t, const float* __restrict__ w,
             const float* __restrict__ c, float* o) {
#pragma unroll
  for (int oo = 0; oo < 8; oo++) {
    float a = c[oo];
#pragma unroll
    for (int i = 0; i < 8; i++) a += t[i] * w[oo * 8 + i];
    o[oo] = a;
  }
}

// ---------------- K0: weight convert + DynamicPosBias MLP (fused, disjoint blocks) ----------------
__global__ void ca_setup(
    const float* __restrict__ qkv_w, const float* __restrict__ proj_w,
    short* __restrict__ wq, short* __restrict__ wp,
    const float* __restrict__ pw, const float* __restrict__ pb,
    const float* __restrict__ g1, const float* __restrict__ b1,
    const float* __restrict__ w1, const float* __restrict__ c1,
    const float* __restrict__ g2, const float* __restrict__ b2,
    const float* __restrict__ w2, const float* __restrict__ c2,
    const float* __restrict__ g3, const float* __restrict__ b3,
    const float* __restrict__ w3, const float* __restrict__ c3,
    float* __restrict__ pos_out) {
  const int blk = blockIdx.x;
  if (blk < 256) {
    int i = blk * 256 + threadIdx.x;  // 65536 threads
    if (i < 49152) {
      float f = qkv_w[i];
      if (i < 16384) f *= QSCALE;  // q rows: fold scale*log2e
      wq[i] = f2b(f);
    } else {
      wp[i - 49152] = f2b(proj_w[i - 49152]);
    }
    return;
  }
  int r = (blk - 256) * 256 + threadIdx.x;
  if (r >= 3375) return;
  float x0 = (float)(r / 225 - 7);
  float x1 = (float)((r / 15) % 15 - 7);
  float x2 = (float)(r % 15 - 7);
  float v[8], t[8], u[8];
#pragma unroll
  for (int o = 0; o < 8; o++)
    v[o] = x0 * pw[o * 3] + x1 * pw[o * 3 + 1] + x2 * pw[o * 3 + 2] + pb[o];
  ln_relu8(v, g1, b1, t);
  mm8(t, w1, c1, u);
  ln_relu8(u, g2, b2, t);
  mm8(t, w2, c2, v);
  ln_relu8(v, g3, b3, t);
#pragma unroll
  for (int hh = 0; hh < 4; hh++) {
    float a = c3[hh];
#pragma unroll
    for (int i = 0; i < 8; i++) a += t[i] * w3[hh * 8 + i];
    pos_out[r * 4 + hh] = a * LOG2E;  // log2 domain for exp2-softmax
  }
}

// ---------------- K1: fused QKV projection (bf16 weights) + rpb frag expand ----------------
// blocks 0..511    : x -> qfrag
// blocks 512..1023 : y -> kfrag + vfrag (V with PV j-permutation baked in)
// blocks 1024..2047: rpbf expansion (one gid per thread, reads posb from global)
__global__ __launch_bounds__(256) void ca_qkv_rpb(
    const float* __restrict__ x, const float* __restrict__ y,
    const short* __restrict__ wq, const float* __restrict__ qkv_b,
    short* __restrict__ gq, short* __restrict__ gk, short* __restrict__ gv,
    const float* __restrict__ posb, short* __restrict__ rpbf) {
  __shared__ short lds[16384];  // 32KB: input stage (stride 136), then frag relayout
  const int blk = blockIdx.x;
  const int tid = threadIdx.x;

  if (blk >= 1024) {
    // ---- rpb frag expansion: one output gid per thread ----
    int gid = (blk - 1024) * 256 + tid;  // 262144 threads
    int lane = gid & 63, jc = (gid >> 6) & 31, qg = (gid >> 11) & 31, hh = gid >> 16;
    int q = qg * 16 + (lane & 15);
    int j0 = jc * 16 + (lane >> 4) * 4;
    bf16x4 outv;
#pragma unroll
    for (int r = 0; r < 4; r++) {
      int j = j0 + r;
      int rh = (q >> 6) - (j >> 6) + 7;
      int rw = ((q >> 3) & 7) - ((j >> 3) & 7) + 7;
      int rd = (q & 7) - (j & 7) + 7;
      int idx = (rh * 15 + rw) * 15 + rd;
      outv[r] = f2b(posb[idx * 4 + hh]);
    }
    *(bf16x4*)(rpbf + (size_t)gid * 4) = outv;
    return;
  }

  // ---- qkv path ----
  const int z = blk >> 9;          // 0: x->q, 1: y->k+v
  const int t0 = (blk & 511) * 64;
  const int b_ = t0 >> 9;
  const int n0 = t0 & 511;
  const float* __restrict__ in = (z == 0) ? x : y;
  // coalesced input staging: flat f32x4 per thread (64 tokens x 128, stride 136)
#pragma unroll
  for (int i = 0; i < 8; i++) {
    int flat = i * 1024 + tid * 4;
    f32x4 f = *(const f32x4*)(in + (size_t)t0 * 128 + flat);
    int row = flat >> 7, col = flat & 127;
    bf16x4 hv;
#pragma unroll
    for (int e = 0; e < 4; e++) hv[e] = f2b(f[e]);
    *(bf16x4*)(lds + row * 136 + col) = hv;
  }
  __syncthreads();
  const int w = tid >> 6, lane = tid & 63, lr = lane & 15, lg = lane >> 4;
  bf16x8 afrag[4];
  {
    const short* ap = lds + (w * 16 + lr) * 136 + lg * 8;
#pragma unroll
    for (int k4 = 0; k4 < 4; k4++) afrag[k4] = *(const bf16x8*)(ap + k4 * 32);
  }
  __syncthreads();  // all afrag reads done before relayout overwrites lds

  if (z == 0) {
#pragma unroll
    for (int ct = 0; ct < 8; ct++) {
      const int col = ct * 16;
      float bias = qkv_b[col + lr] * QSCALE;
      f32x4 acc = {bias, bias, bias, bias};
      const short* bp = wq + (size_t)(col + lr) * 128 + lg * 8;
#pragma unroll
      for (int k4 = 0; k4 < 4; k4++) {
        bf16x8 bfr = *(const bf16x8*)(bp + k4 * 32);
        acc = __builtin_amdgcn_mfma_f32_16x16x32_bf16(afrag[k4], bfr, acc, 0, 0, 0);
      }
      const int d = (ct & 1) * 16 + lr;
      const int base = (w * 4 + (ct >> 1)) * 512 + 128 * (d >> 3) + (d & 7);
#pragma unroll
      for (int r = 0; r < 4; r++)
        lds[base + (lg * 4 + r) * 8] = f2b(acc[r]);
    }
  } else {
#pragma unroll
    for (int ct = 0; ct < 16; ct++) {
      const int col = 128 + ct * 16;
      float bias = qkv_b[col + lr];
      f32x4 acc = {bias, bias, bias, bias};
      const short* bp = wq + (size_t)(col + lr) * 128 + lg * 8;
#pragma unroll
      for (int k4 = 0; k4 < 4; k4++) {
        bf16x8 bfr = *(const bf16x8*)(bp + k4 * 32);
        acc = __builtin_amdgcn_mfma_f32_16x16x32_bf16(afrag[k4], bfr, acc, 0, 0, 0);
      }
      if (ct >= 8) {
        // V frag (PV A-operand-compatible j-permuted layout)
        const int hv_ = (ct - 8) >> 1;
        const int dh = (ct - 8) & 1;
        const int base = 8192 + (((hv_ * 2 + (w >> 1)) * 2 + dh) * 512) + lane * 8 + (w & 1) * 4;
        *(unsigned int*)(lds + base)     = pkbf(acc[0], acc[1]);
        *(unsigned int*)(lds + base + 2) = pkbf(acc[2], acc[3]);
      } else {  // K chunk c = w*4 + (ct>>1)
        const int d = (ct & 1) * 16 + lr;
        const int base = (w * 4 + (ct >> 1)) * 512 + 128 * (d >> 3) + (d & 7);
#pragma unroll
        for (int r = 0; r < 4; r++)
          lds[base + (lg * 4 + r) * 8] = f2b(acc[r]);
      }
    }
  }
  __syncthreads();
  // cooperative 1KB-per-wave coalesced chunk stores
  if (z == 0) {
#pragma unroll
    for (int kk = 0; kk < 4; kk++) {
      const int c = kk * 4 + w, hh = c & 3, tg = c >> 2;
      bf16x8 vd = *(const bf16x8*)(lds + c * 512 + lane * 8);
      *(bf16x8*)(gq + (((size_t)b_ * 4 + hh) * 32 + (n0 >> 4) + tg) * 512 + lane * 8) = vd;
    }
  } else {
#pragma unroll
    for (int kk = 0; kk < 4; kk++) {
      const int c = kk * 4 + w, hh = c & 3, tg = c >> 2;
      bf16x8 vd = *(const bf16x8*)(lds + c * 512 + lane * 8);
      *(bf16x8*)(gk + (((size_t)b_ * 4 + hh) * 32 + (n0 >> 4) + tg) * 512 + lane * 8) = vd;
    }
#pragma unroll
    for (int kk = 0; kk < 4; kk++) {
      const int c = kk * 4 + w, hh = c >> 2, ul = (c >> 1) & 1, dh = c & 1;
      bf16x8 vd = *(const bf16x8*)(lds + 8192 + c * 512 + lane * 8);
      *(bf16x8*)(gv + ((((size_t)b_ * 4 + hh) * 16 + (n0 >> 5) + ul) * 2 + dh) * 512 + lane * 8) = vd;
    }
  }
}

// ---------------- K2: fused attention (dbuf, 4 waves, 1 qg/wave) ----------------
DEV void stage_kv(const short* kg, const short* vg, short* buf, int T, int w, int lane) {
#pragma unroll
  for (int i = 0; i < 4; i++) {
    const int c = w * 4 + i;
    const short* src;
    short* dst;
    if (c < 8) {
      src = kg + ((size_t)(T * 8 + c)) * 512 + lane * 8;
      dst = buf + c * 512;
    } else {
      src = vg + ((size_t)(T * 8 + c - 8)) * 512 + lane * 8;
      dst = buf + 4096 + (c - 8) * 512;
    }
    __builtin_amdgcn_global_load_lds((const __attribute__((address_space(1))) void*)src,
                                     (__attribute__((address_space(3))) void*)dst, 16, 0, 0);
  }
}

__global__ __launch_bounds__(256, 4) void ca_attn(
    const short* __restrict__ qfrag, const short* __restrict__ kfrag,
    const short* __restrict__ vfrag, const short* __restrict__ rpbf,
    short* __restrict__ aob) {
  __shared__ short kv[2][8192];  // dbuf: K tile 8KB | V tile 8KB (per buf 16KB)
  const int bid = blockIdx.x;
  // XCD swizzle: the 8 qt-blocks of one (b,h) share bid%256 -> same XCD slot
  const int qt = bid >> 8, rem = bid & 255;
  const int b_ = rem >> 2, hh = rem & 3;
  const int bh = b_ * 4 + hh;
  const int tid = threadIdx.x;
  const int w = tid >> 6, lane = tid & 63, lg = lane >> 4;
  const int q0 = qt * 64 + w * 16, qg = (q0 >> 4);

  const short* kg = kfrag + (size_t)bh * 16384;
  const short* vg = vfrag + (size_t)bh * 16384;
  const bf16x8 qf = *(const bf16x8*)(qfrag + ((size_t)bh * 32 + qg) * 512 + lane * 8);
  const short* bp = rpbf + ((size_t)(hh * 32 + qg) << 13) + lane * 4;

  union PU { bf16x8 v; unsigned int u[4]; };
  PU ones;
  ones.u[0] = 0x3F803F80u; ones.u[1] = 0x3F803F80u;
  ones.u[2] = 0x3F803F80u; ones.u[3] = 0x3F803F80u;

  stage_kv(kg, vg, &kv[0][0], 0, w, lane);
  __syncthreads();

  f32x4 o0 = {0.f, 0.f, 0.f, 0.f}, o1 = {0.f, 0.f, 0.f, 0.f}, o2 = {0.f, 0.f, 0.f, 0.f};

  for (int T = 0; T < 4; T++) {
    const int cur = T & 1;
    if (T < 3) stage_kv(kg, vg, &kv[cur ^ 1][0], T + 1, w, lane);
    const short* kt = &kv[cur][0];
    const short* vt = &kv[cur][4096];

    u32x2 bw[8];
#pragma unroll
    for (int t = 0; t < 8; t++) bw[t] = *(const u32x2*)(bp + (size_t)(T * 8 + t) * 256);

#pragma unroll
    for (int uu = 0; uu < 4; uu++) {
      PU p;
#pragma unroll
      for (int half = 0; half < 2; half++) {
        const int t = uu * 2 + half;
        bf16x8 kf = *(const bf16x8*)(kt + t * 512 + lane * 8);
        f32x4 cin;
        cin[0] = b2f(bw[t].x << 16);
        cin[1] = b2f(bw[t].x & 0xFFFF0000u);
        cin[2] = b2f(bw[t].y << 16);
        cin[3] = b2f(bw[t].y & 0xFFFF0000u);
        f32x4 s = __builtin_amdgcn_mfma_f32_16x16x32_bf16(kf, qf, cin, 0, 0, 0);
        // no-max softmax: scores bounded (|s| < ~1), exp2 direct is exact-ratio
        p.u[half * 2 + 0] = pkbf(__builtin_exp2f(s[0]), __builtin_exp2f(s[1]));
        p.u[half * 2 + 1] = pkbf(__builtin_exp2f(s[2]), __builtin_exp2f(s[3]));
      }
      bf16x8 vf0 = *(const bf16x8*)(vt + (uu * 2 + 0) * 512 + lane * 8);
      bf16x8 vf1 = *(const bf16x8*)(vt + (uu * 2 + 1) * 512 + lane * 8);
      o0 = __builtin_amdgcn_mfma_f32_16x16x32_bf16(p.v, vf0, o0, 0, 0, 0);
      o1 = __builtin_amdgcn_mfma_f32_16x16x32_bf16(p.v, vf1, o1, 0, 0, 0);
      o2 = __builtin_amdgcn_mfma_f32_16x16x32_bf16(p.v, ones.v, o2, 0, 0, 0);
    }
    if (T < 3) __syncthreads();
  }

  // epilogue: o2[r] = row-sum for q = lg*4+r; normalize + transpose via wave-private LDS
  short* pt = &kv[0][w * 1024];
  const int lr = lane & 15;
#pragma unroll
  for (int r = 0; r < 4; r++) {
    float iv = 1.0f / o2[r];
    pt[(lg * 4 + r) * 40 + lr] = f2b(o0[r] * iv);
    pt[(lg * 4 + r) * 40 + 16 + lr] = f2b(o1[r] * iv);
  }
  asm volatile("s_waitcnt lgkmcnt(0)" ::: "memory");
  __builtin_amdgcn_sched_barrier(0);
  {
    const int qq = lane >> 2, pp = lane & 3;
    bf16x8 od = *(const bf16x8*)(pt + qq * 40 + pp * 8);
    *(bf16x8*)(aob + ((size_t)bh * 512 + q0 + qq) * 32 + pp * 8) = od;  // 1KB/wave coalesced
  }
}

// ---------------- K3: output projection (bf16 weights, LDS-transposed stores) ----------------
__global__ __launch_bounds__(256) void ca_proj(
    const short* __restrict__ aob, const short* __restrict__ wp,
    const float* __restrict__ proj_b, float* __restrict__ out) {
  __shared__ float plds[8448];  // 4 waves x 16x132 f32
  const int t0 = blockIdx.x * 64;
  const int b_ = t0 >> 9, n0 = t0 & 511;
  const int tid = threadIdx.x;
  const int w = tid >> 6, lane = tid & 63, lr = lane & 15, lg = lane >> 4;
  bf16x8 afrag[4];
#pragma unroll
  for (int k4 = 0; k4 < 4; k4++)
    afrag[k4] = *(const bf16x8*)(aob + (((size_t)b_ * 4 + k4) * 512 + n0 + w * 16 + lr) * 32 + lg * 8);
  float* pt = plds + w * 2112;
#pragma unroll
  for (int ct = 0; ct < 8; ct++) {
    float bias = proj_b[ct * 16 + lr];
    f32x4 acc = {bias, bias, bias, bias};
    const short* bp = wp + (size_t)(ct * 16 + lr) * 128 + lg * 8;
#pragma unroll
    for (int k4 = 0; k4 < 4; k4++) {
      bf16x8 bfr = *(const bf16x8*)(bp + k4 * 32);
      acc = __builtin_amdgcn_mfma_f32_16x16x32_bf16(afrag[k4], bfr, acc, 0, 0, 0);
    }
#pragma unroll
    for (int r = 0; r < 4; r++)
      pt[(lg * 4 + r) * 132 + ct * 16 + lr] = acc[r];
  }
  asm volatile("s_waitcnt lgkmcnt(0)" ::: "memory");
  __builtin_amdgcn_sched_barrier(0);
#pragma unroll
  for (int i = 0; i < 8; i++) {
    int f = i * 256 + lane * 4;
    int row = f >> 7, col = f & 127;
    f32x4 v = *(const f32x4*)(pt + row * 132 + col);
    *(f32x4*)(out + (size_t)(t0 + w * 16) * 128 + f) = v;  // dense 1KB/wave stores
  }
}

extern "C" void kernel_launch(void* const* d_in, const int* in_sizes, int n_in,
                              void* d_out, int out_size, void* d_ws, size_t ws_size,
                              hipStream_t stream) {
  const float* x      = (const float*)d_in[0];
  const float* y      = (const float*)d_in[1];
  const float* qkv_w  = (const float*)d_in[5];
  const float* qkv_b  = (const float*)d_in[6];
  const float* proj_w = (const float*)d_in[7];
  const float* proj_b = (const float*)d_in[8];
  const float* pos_w  = (const float*)d_in[9];
  const float* pos_b  = (const float*)d_in[10];
  const float* ln1g = (const float*)d_in[11];
  const float* ln1b = (const float*)d_in[12];
  const float* p1w  = (const float*)d_in[13];
  const float* p1b  = (const float*)d_in[14];
  const float* ln2g = (const float*)d_in[15];
  const float* ln2b = (const float*)d_in[16];
  const float* p2w  = (const float*)d_in[17];
  const float* p2b  = (const float*)d_in[18];
  const float* ln3g = (const float*)d_in[19];
  const float* ln3b = (const float*)d_in[20];
  const float* p3w  = (const float*)d_in[21];
  const float* p3b  = (const float*)d_in[22];
  float* out = (float*)d_out;

  char* ws = (char*)d_ws;
  short* gq    = (short*)(ws + OFF_Q);
  short* gk    = (short*)(ws + OFF_K);
  short* gv    = (short*)(ws + OFF_V);
  short* rpbf  = (short*)(ws + OFF_RPB);
  short* aob   = (short*)(ws + OFF_AO);
  float* posb  = (float*)(ws + OFF_POS);
  short* wq    = (short*)(ws + OFF_WQ);
  short* wp    = (short*)(ws + OFF_WP);

  ca_setup<<<270, 256, 0, stream>>>(qkv_w, proj_w, wq, wp,
                                    pos_w, pos_b, ln1g, ln1b, p1w, p1b,
                                    ln2g, ln2b, p2w, p2b, ln3g, ln3b, p3w, p3b, posb);
  ca_qkv_rpb<<<2048, 256, 0, stream>>>(x, y, wq, qkv_b, gq, gk, gv, posb, rpbf);
  ca_attn<<<2048, 256, 0, stream>>>(gq, gk, gv, rpbf, aob);
  ca_proj<<<512, 256, 0, stream>>>(aob, wp, proj_b, out);
}

// Round 10
// 78.557 us; speedup vs baseline: 1.3878x; 1.0220x over previous
//
#include <hip/hip_runtime.h>
#include <hip/hip_bf16.h>

typedef __attribute__((ext_vector_type(4))) float f32x4;
typedef __attribute__((ext_vector_type(8))) short bf16x8;
typedef __attribute__((ext_vector_type(4))) short bf16x4;
typedef __attribute__((ext_vector_type(2))) unsigned int u32x2;

#define DEV static __device__ __forceinline__

constexpr float LOG2E  = 1.4426950408889634f;
constexpr float QSCALE = 0.17677669529663687f * LOG2E;  // hd^-0.5 * log2e

// ws layout (bytes)
constexpr size_t OFF_Q   = 0;                    // bf16 frag Q  (256 bh x 32 qg x 512)
constexpr size_t OFF_K   = (size_t)8  << 20;     // bf16 frag K  (256 bh x 32 tg x 512)
constexpr size_t OFF_V   = (size_t)16 << 20;     // bf16 frag V  (256 bh x 16 ug x 2 dh x 512), j-permuted
constexpr size_t OFF_RPB = (size_t)24 << 20;     // bf16 frag bias (4 h x 32 qg x 32 jc x 64 lane x 4)
constexpr size_t OFF_AO  = (size_t)27 << 20;     // bf16 head-major (bh, n, 32)
constexpr size_t OFF_POS = (size_t)35 << 20;     // f32  (3375, 4)
constexpr size_t OFF_WQ  = (size_t)36 << 20;     // bf16 (384, 128)
constexpr size_t OFF_WP  = (size_t)37 << 20;     // bf16 (128, 128)

DEV short f2b(float f) {
  union { __bf16 h; short s; } u;
  u.h = (__bf16)f;
  return u.s;
}
DEV float b2f(unsigned int u) {
  union { unsigned int u; float f; } x; x.u = u; return x.f;
}
DEV unsigned int pkbf(float a, float b) {
  union { __bf16 h; unsigned short s; } ua, ub;
  ua.h = (__bf16)a; ub.h = (__bf16)b;
  return (unsigned int)ua.s | ((unsigned int)ub.s << 16);
}

// ---------------- helpers: tiny MLP ----------------
DEV void ln_relu8(const float* v, const float* __restrict__ g,
                  const float* __restrict__ b, float* t) {
  float m = 0.f;
#pragma unroll
  for (int i = 0; i < 8; i++) m += v[i];
  m *= 0.125f;
  float var = 0.f;
#pragma unroll
  for (int i = 0; i < 8; i++) { float d = v[i] - m; var += d * d; }
  var *= 0.125f;
  float inv = 1.0f / sqrtf(var + 1e-5f);
#pragma unroll
  for (int i = 0; i < 8; i++) {
    float u = (v[i] - m) * inv * g[i] + b[i];
    t[i] = u > 0.f ? u : 0.f;
  }
}

DEV void mm8(const float* t, const float* __restrict__ w,
             const float* __restrict__ c, float* o) {
#pragma unroll
  for (int oo = 0; oo < 8; oo++) {
    float a = c[oo];
#pragma unroll
    for (int i = 0; i < 8; i++) a += t[i] * w[oo * 8 + i];
    o[oo] = a;
  }
}

// ---------------- K0: weight convert + DynamicPosBias MLP (fused, disjoint blocks) ----------------
__global__ void ca_setup(
    const float* __restrict__ qkv_w, const float* __restrict__ proj_w,
    short* __restrict__ wq, short* __restrict__ wp,
    const float* __restrict__ pw, const float* __restrict__ pb,
    const float* __restrict__ g1, const float* __restrict__ b1,
    const float* __restrict__ w1, const float* __restrict__ c1,
    const float* __restrict__ g2, const float* __restrict__ b2,
    const float* __restrict__ w2, const float* __restrict__ c2,
    const float* __restrict__ g3, const float* __restrict__ b3,
    const float* __restrict__ w3, const float* __restrict__ c3,
    float* __restrict__ pos_out) {
  const int blk = blockIdx.x;
  if (blk < 256) {
    int i = blk * 256 + threadIdx.x;  // 65536 threads
    if (i < 49152) {
      float f = qkv_w[i];
      if (i < 16384) f *= QSCALE;  // q rows: fold scale*log2e
      wq[i] = f2b(f);
    } else {
      wp[i - 49152] = f2b(proj_w[i - 49152]);
    }
    return;
  }
  int r = (blk - 256) * 256 + threadIdx.x;
  if (r >= 3375) return;
  float x0 = (float)(r / 225 - 7);
  float x1 = (float)((r / 15) % 15 - 7);
  float x2 = (float)(r % 15 - 7);
  float v[8], t[8], u[8];
#pragma unroll
  for (int o = 0; o < 8; o++)
    v[o] = x0 * pw[o * 3] + x1 * pw[o * 3 + 1] + x2 * pw[o * 3 + 2] + pb[o];
  ln_relu8(v, g1, b1, t);
  mm8(t, w1, c1, u);
  ln_relu8(u, g2, b2, t);
  mm8(t, w2, c2, v);
  ln_relu8(v, g3, b3, t);
#pragma unroll
  for (int hh = 0; hh < 4; hh++) {
    float a = c3[hh];
#pragma unroll
    for (int i = 0; i < 8; i++) a += t[i] * w3[hh * 8 + i];
    pos_out[r * 4 + hh] = a * LOG2E;  // log2 domain for exp2-softmax
  }
}

// ---------------- K1: fused QKV projection (bf16 weights) + rpb frag expand ----------------
// blocks 0..511    : x -> qfrag
// blocks 512..1023 : y -> kfrag + vfrag (V with PV j-permutation baked in)
// blocks 1024..2047: rpbf expansion (one gid per thread, reads posb from global)
__global__ __launch_bounds__(256) void ca_qkv_rpb(
    const float* __restrict__ x, const float* __restrict__ y,
    const short* __restrict__ wq, const float* __restrict__ qkv_b,
    short* __restrict__ gq, short* __restrict__ gk, short* __restrict__ gv,
    const float* __restrict__ posb, short* __restrict__ rpbf) {
  __shared__ short lds[16384];  // 32KB: input stage (stride 136), then frag relayout
  const int blk = blockIdx.x;
  const int tid = threadIdx.x;

  if (blk >= 1024) {
    // ---- rpb frag expansion: one output gid per thread ----
    int gid = (blk - 1024) * 256 + tid;  // 262144 threads
    int lane = gid & 63, jc = (gid >> 6) & 31, qg = (gid >> 11) & 31, hh = gid >> 16;
    int q = qg * 16 + (lane & 15);
    int j0 = jc * 16 + (lane >> 4) * 4;
    bf16x4 outv;
#pragma unroll
    for (int r = 0; r < 4; r++) {
      int j = j0 + r;
      int rh = (q >> 6) - (j >> 6) + 7;
      int rw = ((q >> 3) & 7) - ((j >> 3) & 7) + 7;
      int rd = (q & 7) - (j & 7) + 7;
      int idx = (rh * 15 + rw) * 15 + rd;
      outv[r] = f2b(posb[idx * 4 + hh]);
    }
    *(bf16x4*)(rpbf + (size_t)gid * 4) = outv;
    return;
  }

  // ---- qkv path ----
  const int z = blk >> 9;          // 0: x->q, 1: y->k+v
  const int t0 = (blk & 511) * 64;
  const int b_ = t0 >> 9;
  const int n0 = t0 & 511;
  const float* __restrict__ in = (z == 0) ? x : y;
  // coalesced input staging: flat f32x4 per thread (64 tokens x 128, stride 136)
#pragma unroll
  for (int i = 0; i < 8; i++) {
    int flat = i * 1024 + tid * 4;
    f32x4 f = *(const f32x4*)(in + (size_t)t0 * 128 + flat);
    int row = flat >> 7, col = flat & 127;
    bf16x4 hv;
#pragma unroll
    for (int e = 0; e < 4; e++) hv[e] = f2b(f[e]);
    *(bf16x4*)(lds + row * 136 + col) = hv;
  }
  __syncthreads();
  const int w = tid >> 6, lane = tid & 63, lr = lane & 15, lg = lane >> 4;
  bf16x8 afrag[4];
  {
    const short* ap = lds + (w * 16 + lr) * 136 + lg * 8;
#pragma unroll
    for (int k4 = 0; k4 < 4; k4++) afrag[k4] = *(const bf16x8*)(ap + k4 * 32);
  }
  __syncthreads();  // all afrag reads done before relayout overwrites lds

  if (z == 0) {
#pragma unroll
    for (int ct = 0; ct < 8; ct++) {
      const int col = ct * 16;
      float bias = qkv_b[col + lr] * QSCALE;
      f32x4 acc = {bias, bias, bias, bias};
      const short* bp = wq + (size_t)(col + lr) * 128 + lg * 8;
#pragma unroll
      for (int k4 = 0; k4 < 4; k4++) {
        bf16x8 bfr = *(const bf16x8*)(bp + k4 * 32);
        acc = __builtin_amdgcn_mfma_f32_16x16x32_bf16(afrag[k4], bfr, acc, 0, 0, 0);
      }
      const int d = (ct & 1) * 16 + lr;
      const int base = (w * 4 + (ct >> 1)) * 512 + 128 * (d >> 3) + (d & 7);
#pragma unroll
      for (int r = 0; r < 4; r++)
        lds[base + (lg * 4 + r) * 8] = f2b(acc[r]);
    }
  } else {
#pragma unroll
    for (int ct = 0; ct < 16; ct++) {
      const int col = 128 + ct * 16;
      float bias = qkv_b[col + lr];
      f32x4 acc = {bias, bias, bias, bias};
      const short* bp = wq + (size_t)(col + lr) * 128 + lg * 8;
#pragma unroll
      for (int k4 = 0; k4 < 4; k4++) {
        bf16x8 bfr = *(const bf16x8*)(bp + k4 * 32);
        acc = __builtin_amdgcn_mfma_f32_16x16x32_bf16(afrag[k4], bfr, acc, 0, 0, 0);
      }
      if (ct >= 8) {
        // V frag (PV A-operand-compatible j-permuted layout)
        const int hv_ = (ct - 8) >> 1;
        const int dh = (ct - 8) & 1;
        const int base = 8192 + (((hv_ * 2 + (w >> 1)) * 2 + dh) * 512) + lane * 8 + (w & 1) * 4;
        *(unsigned int*)(lds + base)     = pkbf(acc[0], acc[1]);
        *(unsigned int*)(lds + base + 2) = pkbf(acc[2], acc[3]);
      } else {  // K chunk c = w*4 + (ct>>1)
        const int d = (ct & 1) * 16 + lr;
        const int base = (w * 4 + (ct >> 1)) * 512 + 128 * (d >> 3) + (d & 7);
#pragma unroll
        for (int r = 0; r < 4; r++)
          lds[base + (lg * 4 + r) * 8] = f2b(acc[r]);
      }
    }
  }
  __syncthreads();
  // cooperative 1KB-per-wave coalesced chunk stores
  if (z == 0) {
#pragma unroll
    for (int kk = 0; kk < 4; kk++) {
      const int c = kk * 4 + w, hh = c & 3, tg = c >> 2;
      bf16x8 vd = *(const bf16x8*)(lds + c * 512 + lane * 8);
      *(bf16x8*)(gq + (((size_t)b_ * 4 + hh) * 32 + (n0 >> 4) + tg) * 512 + lane * 8) = vd;
    }
  } else {
#pragma unroll
    for (int kk = 0; kk < 4; kk++) {
      const int c = kk * 4 + w, hh = c & 3, tg = c >> 2;
      bf16x8 vd = *(const bf16x8*)(lds + c * 512 + lane * 8);
      *(bf16x8*)(gk + (((size_t)b_ * 4 + hh) * 32 + (n0 >> 4) + tg) * 512 + lane * 8) = vd;
    }
#pragma unroll
    for (int kk = 0; kk < 4; kk++) {
      const int c = kk * 4 + w, hh = c >> 2, ul = (c >> 1) & 1, dh = c & 1;
      bf16x8 vd = *(const bf16x8*)(lds + 8192 + c * 512 + lane * 8);
      *(bf16x8*)(gv + ((((size_t)b_ * 4 + hh) * 16 + (n0 >> 5) + ul) * 2 + dh) * 512 + lane * 8) = vd;
    }
  }
}

// ---------------- K2: fused attention (dbuf, 8 waves, 128 q-rows/block) ----------------
DEV void stage_kv8(const short* kg, const short* vg, short* buf, int T, int w, int lane) {
#pragma unroll
  for (int i = 0; i < 2; i++) {
    const int c = w * 2 + i;  // 16 chunks: 0..7 K, 8..15 V
    const short* src;
    short* dst;
    if (c < 8) {
      src = kg + ((size_t)(T * 8 + c)) * 512 + lane * 8;
      dst = buf + c * 512;
    } else {
      src = vg + ((size_t)(T * 8 + c - 8)) * 512 + lane * 8;
      dst = buf + 4096 + (c - 8) * 512;
    }
    __builtin_amdgcn_global_load_lds((const __attribute__((address_space(1))) void*)src,
                                     (__attribute__((address_space(3))) void*)dst, 16, 0, 0);
  }
}

__global__ __launch_bounds__(512, 8) void ca_attn(
    const short* __restrict__ qfrag, const short* __restrict__ kfrag,
    const short* __restrict__ vfrag, const short* __restrict__ rpbf,
    short* __restrict__ aob) {
  __shared__ short kv[2][8192];  // dbuf: K tile 8KB | V tile 8KB (per buf 16KB) = 32KB total
  const int bid = blockIdx.x;
  // XCD swizzle: the 4 qt2-blocks of one (b,h) are bid = rem + k*256 -> same XCD (256%8==0)
  const int qt2 = bid >> 8, rem = bid & 255;
  const int b_ = rem >> 2, hh = rem & 3;
  const int bh = b_ * 4 + hh;
  const int tid = threadIdx.x;
  const int w = tid >> 6, lane = tid & 63, lg = lane >> 4;
  const int qg = qt2 * 8 + w;      // one q-group (16 rows) per wave, 8 waves = 128 rows
  const int q0 = qg * 16;

  const short* kg = kfrag + (size_t)bh * 16384;
  const short* vg = vfrag + (size_t)bh * 16384;
  const bf16x8 qf = *(const bf16x8*)(qfrag + ((size_t)bh * 32 + qg) * 512 + lane * 8);
  const short* bp = rpbf + ((size_t)(hh * 32 + qg) << 13) + lane * 4;

  union PU { bf16x8 v; unsigned int u[4]; };
  PU ones;
  ones.u[0] = 0x3F803F80u; ones.u[1] = 0x3F803F80u;
  ones.u[2] = 0x3F803F80u; ones.u[3] = 0x3F803F80u;

  stage_kv8(kg, vg, &kv[0][0], 0, w, lane);
  __syncthreads();

  f32x4 o0 = {0.f, 0.f, 0.f, 0.f}, o1 = {0.f, 0.f, 0.f, 0.f}, o2 = {0.f, 0.f, 0.f, 0.f};

  for (int T = 0; T < 4; T++) {
    const int cur = T & 1;
    if (T < 3) stage_kv8(kg, vg, &kv[cur ^ 1][0], T + 1, w, lane);
    const short* kt = &kv[cur][0];
    const short* vt = &kv[cur][4096];

    u32x2 bw[8];
#pragma unroll
    for (int t = 0; t < 8; t++) bw[t] = *(const u32x2*)(bp + (size_t)(T * 8 + t) * 256);

#pragma unroll
    for (int uu = 0; uu < 4; uu++) {
      PU p;
#pragma unroll
      for (int half = 0; half < 2; half++) {
        const int t = uu * 2 + half;
        bf16x8 kf = *(const bf16x8*)(kt + t * 512 + lane * 8);
        f32x4 cin;
        cin[0] = b2f(bw[t].x << 16);
        cin[1] = b2f(bw[t].x & 0xFFFF0000u);
        cin[2] = b2f(bw[t].y << 16);
        cin[3] = b2f(bw[t].y & 0xFFFF0000u);
        f32x4 s = __builtin_amdgcn_mfma_f32_16x16x32_bf16(kf, qf, cin, 0, 0, 0);
        // no-max softmax: scores bounded (|s| < ~1), exp2 direct is exact-ratio
        p.u[half * 2 + 0] = pkbf(__builtin_exp2f(s[0]), __builtin_exp2f(s[1]));
        p.u[half * 2 + 1] = pkbf(__builtin_exp2f(s[2]), __builtin_exp2f(s[3]));
      }
      bf16x8 vf0 = *(const bf16x8*)(vt + (uu * 2 + 0) * 512 + lane * 8);
      bf16x8 vf1 = *(const bf16x8*)(vt + (uu * 2 + 1) * 512 + lane * 8);
      o0 = __builtin_amdgcn_mfma_f32_16x16x32_bf16(p.v, vf0, o0, 0, 0, 0);
      o1 = __builtin_amdgcn_mfma_f32_16x16x32_bf16(p.v, vf1, o1, 0, 0, 0);
      o2 = __builtin_amdgcn_mfma_f32_16x16x32_bf16(p.v, ones.v, o2, 0, 0, 0);
    }
    if (T < 3) __syncthreads();
  }

  // epilogue: o2[r] = row-sum for q = lg*4+r; normalize + transpose via wave-private LDS
  // last tile used kv[1]; kv[0] (16KB) is dead -> 8 waves x 1024 shorts
  short* pt = &kv[0][w * 1024];
  const int lr = lane & 15;
#pragma unroll
  for (int r = 0; r < 4; r++) {
    float iv = 1.0f / o2[r];
    pt[(lg * 4 + r) * 40 + lr] = f2b(o0[r] * iv);
    pt[(lg * 4 + r) * 40 + 16 + lr] = f2b(o1[r] * iv);
  }
  asm volatile("s_waitcnt lgkmcnt(0)" ::: "memory");
  __builtin_amdgcn_sched_barrier(0);
  {
    const int qq = lane >> 2, pp = lane & 3;
    bf16x8 od = *(const bf16x8*)(pt + qq * 40 + pp * 8);
    *(bf16x8*)(aob + ((size_t)bh * 512 + q0 + qq) * 32 + pp * 8) = od;  // 1KB/wave coalesced
  }
}

// ---------------- K3: output projection (bf16 weights, LDS-transposed stores) ----------------
__global__ __launch_bounds__(256) void ca_proj(
    const short* __restrict__ aob, const short* __restrict__ wp,
    const float* __restrict__ proj_b, float* __restrict__ out) {
  __shared__ float plds[8448];  // 4 waves x 16x132 f32
  const int t0 = blockIdx.x * 64;
  const int b_ = t0 >> 9, n0 = t0 & 511;
  const int tid = threadIdx.x;
  const int w = tid >> 6, lane = tid & 63, lr = lane & 15, lg = lane >> 4;
  bf16x8 afrag[4];
#pragma unroll
  for (int k4 = 0; k4 < 4; k4++)
    afrag[k4] = *(const bf16x8*)(aob + (((size_t)b_ * 4 + k4) * 512 + n0 + w * 16 + lr) * 32 + lg * 8);
  float* pt = plds + w * 2112;
#pragma unroll
  for (int ct = 0; ct < 8; ct++) {
    float bias = proj_b[ct * 16 + lr];
    f32x4 acc = {bias, bias, bias, bias};
    const short* bp = wp + (size_t)(ct * 16 + lr) * 128 + lg * 8;
#pragma unroll
    for (int k4 = 0; k4 < 4; k4++) {
      bf16x8 bfr = *(const bf16x8*)(bp + k4 * 32);
      acc = __builtin_amdgcn_mfma_f32_16x16x32_bf16(afrag[k4], bfr, acc, 0, 0, 0);
    }
#pragma unroll
    for (int r = 0; r < 4; r++)
      pt[(lg * 4 + r) * 132 + ct * 16 + lr] = acc[r];
  }
  asm volatile("s_waitcnt lgkmcnt(0)" ::: "memory");
  __builtin_amdgcn_sched_barrier(0);
#pragma unroll
  for (int i = 0; i < 8; i++) {
    int f = i * 256 + lane * 4;
    int row = f >> 7, col = f & 127;
    f32x4 v = *(const f32x4*)(pt + row * 132 + col);
    *(f32x4*)(out + (size_t)(t0 + w * 16) * 128 + f) = v;  // dense 1KB/wave stores
  }
}

extern "C" void kernel_launch(void* const* d_in, const int* in_sizes, int n_in,
                              void* d_out, int out_size, void* d_ws, size_t ws_size,
                              hipStream_t stream) {
  const float* x      = (const float*)d_in[0];
  const float* y      = (const float*)d_in[1];
  const float* qkv_w  = (const float*)d_in[5];
  const float* qkv_b  = (const float*)d_in[6];
  const float* proj_w = (const float*)d_in[7];
  const float* proj_b = (const float*)d_in[8];
  const float* pos_w  = (const float*)d_in[9];
  const float* pos_b  = (const float*)d_in[10];
  const float* ln1g = (const float*)d_in[11];
  const float* ln1b = (const float*)d_in[12];
  const float* p1w  = (const float*)d_in[13];
  const float* p1b  = (const float*)d_in[14];
  const float* ln2g = (const float*)d_in[15];
  const float* ln2b = (const float*)d_in[16];
  const float* p2w  = (const float*)d_in[17];
  const float* p2b  = (const float*)d_in[18];
  const float* ln3g = (const float*)d_in[19];
  const float* ln3b = (const float*)d_in[20];
  const float* p3w  = (const float*)d_in[21];
  const float* p3b  = (const float*)d_in[22];
  float* out = (float*)d_out;

  char* ws = (char*)d_ws;
  short* gq    = (short*)(ws + OFF_Q);
  short* gk    = (short*)(ws + OFF_K);
  short* gv    = (short*)(ws + OFF_V);
  short* rpbf  = (short*)(ws + OFF_RPB);
  short* aob   = (short*)(ws + OFF_AO);
  float* posb  = (float*)(ws + OFF_POS);
  short* wq    = (short*)(ws + OFF_WQ);
  short* wp    = (short*)(ws + OFF_WP);

  ca_setup<<<270, 256, 0, stream>>>(qkv_w, proj_w, wq, wp,
                                    pos_w, pos_b, ln1g, ln1b, p1w, p1b,
                                    ln2g, ln2b, p2w, p2b, ln3g, ln3b, p3w, p3b, posb);
  ca_qkv_rpb<<<2048, 256, 0, stream>>>(x, y, wq, qkv_b, gq, gk, gv, posb, rpbf);
  ca_attn<<<1024, 512, 0, stream>>>(gq, gk, gv, rpbf, aob);
  ca_proj<<<512, 256, 0, stream>>>(aob, wp, proj_b, out);
}

// Round 11
// 78.283 us; speedup vs baseline: 1.3926x; 1.0035x over previous
//
#include <hip/hip_runtime.h>
#include <hip/hip_bf16.h>

typedef __attribute__((ext_vector_type(4))) float f32x4;
typedef __attribute__((ext_vector_type(8))) short bf16x8;
typedef __attribute__((ext_vector_type(4))) short bf16x4;
typedef __attribute__((ext_vector_type(2))) unsigned int u32x2;

#define DEV static __device__ __forceinline__

constexpr float LOG2E  = 1.4426950408889634f;
constexpr float QSCALE = 0.17677669529663687f * LOG2E;  // hd^-0.5 * log2e

// ws layout (bytes)
constexpr size_t OFF_Q   = 0;                    // bf16 frag Q  (256 bh x 32 qg x 512)
constexpr size_t OFF_K   = (size_t)8  << 20;     // bf16 frag K  (256 bh x 32 tg x 512)
constexpr size_t OFF_V   = (size_t)16 << 20;     // bf16 frag V  (256 bh x 16 ug x 2 dh x 512), j-permuted
constexpr size_t OFF_RPB = (size_t)24 << 20;     // bf16 frag bias (4 h x 32 qg x 32 jc x 64 lane x 4)
constexpr size_t OFF_AO  = (size_t)27 << 20;     // bf16 head-major (bh, n, 32)
constexpr size_t OFF_POS = (size_t)35 << 20;     // f32  (3375, 4)
constexpr size_t OFF_WQ  = (size_t)36 << 20;     // bf16 (384, 128)
constexpr size_t OFF_WP  = (size_t)37 << 20;     // bf16 (128, 128)

DEV short f2b(float f) {
  union { __bf16 h; short s; } u;
  u.h = (__bf16)f;
  return u.s;
}
DEV float b2f(unsigned int u) {
  union { unsigned int u; float f; } x; x.u = u; return x.f;
}
DEV unsigned int pkbf(float a, float b) {
  union { __bf16 h; unsigned short s; } ua, ub;
  ua.h = (__bf16)a; ub.h = (__bf16)b;
  return (unsigned int)ua.s | ((unsigned int)ub.s << 16);
}

// ---------------- helpers: tiny MLP ----------------
DEV void ln_relu8(const float* v, const float* __restrict__ g,
                  const float* __restrict__ b, float* t) {
  float m = 0.f;
#pragma unroll
  for (int i = 0; i < 8; i++) m += v[i];
  m *= 0.125f;
  float var = 0.f;
#pragma unroll
  for (int i = 0; i < 8; i++) { float d = v[i] - m; var += d * d; }
  var *= 0.125f;
  float inv = 1.0f / sqrtf(var + 1e-5f);
#pragma unroll
  for (int i = 0; i < 8; i++) {
    float u = (v[i] - m) * inv * g[i] + b[i];
    t[i] = u > 0.f ? u : 0.f;
  }
}

DEV void mm8(const float* t, const float* __restrict__ w,
             const float* __restrict__ c, float* o) {
#pragma unroll
  for (int oo = 0; oo < 8; oo++) {
    float a = c[oo];
#pragma unroll
    for (int i = 0; i < 8; i++) a += t[i] * w[oo * 8 + i];
    o[oo] = a;
  }
}

// ---------------- K0: weight convert + DynamicPosBias MLP (fused, disjoint blocks) ----------------
__global__ void ca_setup(
    const float* __restrict__ qkv_w, const float* __restrict__ proj_w,
    short* __restrict__ wq, short* __restrict__ wp,
    const float* __restrict__ pw, const float* __restrict__ pb,
    const float* __restrict__ g1, const float* __restrict__ b1,
    const float* __restrict__ w1, const float* __restrict__ c1,
    const float* __restrict__ g2, const float* __restrict__ b2,
    const float* __restrict__ w2, const float* __restrict__ c2,
    const float* __restrict__ g3, const float* __restrict__ b3,
    const float* __restrict__ w3, const float* __restrict__ c3,
    float* __restrict__ pos_out) {
  const int blk = blockIdx.x;
  if (blk < 256) {
    int i = blk * 256 + threadIdx.x;  // 65536 threads
    if (i < 49152) {
      float f = qkv_w[i];
      if (i < 16384) f *= QSCALE;  // q rows: fold scale*log2e
      wq[i] = f2b(f);
    } else {
      wp[i - 49152] = f2b(proj_w[i - 49152]);
    }
    return;
  }
  int r = (blk - 256) * 256 + threadIdx.x;
  if (r >= 3375) return;
  float x0 = (float)(r / 225 - 7);
  float x1 = (float)((r / 15) % 15 - 7);
  float x2 = (float)(r % 15 - 7);
  float v[8], t[8], u[8];
#pragma unroll
  for (int o = 0; o < 8; o++)
    v[o] = x0 * pw[o * 3] + x1 * pw[o * 3 + 1] + x2 * pw[o * 3 + 2] + pb[o];
  ln_relu8(v, g1, b1, t);
  mm8(t, w1, c1, u);
  ln_relu8(u, g2, b2, t);
  mm8(t, w2, c2, v);
  ln_relu8(v, g3, b3, t);
#pragma unroll
  for (int hh = 0; hh < 4; hh++) {
    float a = c3[hh];
#pragma unroll
    for (int i = 0; i < 8; i++) a += t[i] * w3[hh * 8 + i];
    pos_out[r * 4 + hh] = a * LOG2E;  // log2 domain for exp2-softmax
  }
}

// ---------------- K1: QKV projection (3 uniform classes) + rpb frag expand ----------------
// blocks 0..511    : x -> qfrag
// blocks 512..1023 : y -> kfrag
// blocks 1024..1535: y -> vfrag (PV j-permuted layout)
// blocks 1536..2559: rpbf expansion (one gid per thread)
__global__ __launch_bounds__(256) void ca_qkv_rpb(
    const float* __restrict__ x, const float* __restrict__ y,
    const short* __restrict__ wq, const float* __restrict__ qkv_b,
    short* __restrict__ gq, short* __restrict__ gk, short* __restrict__ gv,
    const float* __restrict__ posb, short* __restrict__ rpbf) {
  __shared__ short lds[16384];  // 32KB: input stage (stride 136), then frag relayout
  const int blk = blockIdx.x;
  const int tid = threadIdx.x;

  if (blk >= 1536) {
    // ---- rpb frag expansion: one output gid per thread ----
    int gid = (blk - 1536) * 256 + tid;  // 262144 threads
    int lane = gid & 63, jc = (gid >> 6) & 31, qg = (gid >> 11) & 31, hh = gid >> 16;
    int q = qg * 16 + (lane & 15);
    int j0 = jc * 16 + (lane >> 4) * 4;
    bf16x4 outv;
#pragma unroll
    for (int r = 0; r < 4; r++) {
      int j = j0 + r;
      int rh = (q >> 6) - (j >> 6) + 7;
      int rw = ((q >> 3) & 7) - ((j >> 3) & 7) + 7;
      int rd = (q & 7) - (j & 7) + 7;
      int idx = (rh * 15 + rw) * 15 + rd;
      outv[r] = f2b(posb[idx * 4 + hh]);
    }
    *(bf16x4*)(rpbf + (size_t)gid * 4) = outv;
    return;
  }

  // ---- qkv path: z = 0 (q from x), 1 (k from y), 2 (v from y) ----
  const int z = blk >> 9;
  const int t0 = (blk & 511) * 64;
  const int b_ = t0 >> 9;
  const int n0 = t0 & 511;
  const float* __restrict__ in = (z == 0) ? x : y;
  // coalesced input staging: flat f32x4 per thread (64 tokens x 128, stride 136)
#pragma unroll
  for (int i = 0; i < 8; i++) {
    int flat = i * 1024 + tid * 4;
    f32x4 f = *(const f32x4*)(in + (size_t)t0 * 128 + flat);
    int row = flat >> 7, col = flat & 127;
    bf16x4 hv;
#pragma unroll
    for (int e = 0; e < 4; e++) hv[e] = f2b(f[e]);
    *(bf16x4*)(lds + row * 136 + col) = hv;
  }
  __syncthreads();
  const int w = tid >> 6, lane = tid & 63, lr = lane & 15, lg = lane >> 4;
  bf16x8 afrag[4];
  {
    const short* ap = lds + (w * 16 + lr) * 136 + lg * 8;
#pragma unroll
    for (int k4 = 0; k4 < 4; k4++) afrag[k4] = *(const bf16x8*)(ap + k4 * 32);
  }
  __syncthreads();  // all afrag reads done before relayout overwrites lds

  if (z == 0) {
#pragma unroll
    for (int ct = 0; ct < 8; ct++) {
      const int col = ct * 16;
      float bias = qkv_b[col + lr] * QSCALE;
      f32x4 acc = {bias, bias, bias, bias};
      const short* bp = wq + (size_t)(col + lr) * 128 + lg * 8;
#pragma unroll
      for (int k4 = 0; k4 < 4; k4++) {
        bf16x8 bfr = *(const bf16x8*)(bp + k4 * 32);
        acc = __builtin_amdgcn_mfma_f32_16x16x32_bf16(afrag[k4], bfr, acc, 0, 0, 0);
      }
      const int d = (ct & 1) * 16 + lr;
      const int base = (w * 4 + (ct >> 1)) * 512 + 128 * (d >> 3) + (d & 7);
#pragma unroll
      for (int r = 0; r < 4; r++)
        lds[base + (lg * 4 + r) * 8] = f2b(acc[r]);
    }
  } else if (z == 1) {
#pragma unroll
    for (int ct = 0; ct < 8; ct++) {
      const int col = 128 + ct * 16;
      float bias = qkv_b[col + lr];
      f32x4 acc = {bias, bias, bias, bias};
      const short* bp = wq + (size_t)(col + lr) * 128 + lg * 8;
#pragma unroll
      for (int k4 = 0; k4 < 4; k4++) {
        bf16x8 bfr = *(const bf16x8*)(bp + k4 * 32);
        acc = __builtin_amdgcn_mfma_f32_16x16x32_bf16(afrag[k4], bfr, acc, 0, 0, 0);
      }
      const int d = (ct & 1) * 16 + lr;
      const int base = (w * 4 + (ct >> 1)) * 512 + 128 * (d >> 3) + (d & 7);
#pragma unroll
      for (int r = 0; r < 4; r++)
        lds[base + (lg * 4 + r) * 8] = f2b(acc[r]);
    }
  } else {
#pragma unroll
    for (int ct = 0; ct < 8; ct++) {
      const int col = 256 + ct * 16;
      float bias = qkv_b[col + lr];
      f32x4 acc = {bias, bias, bias, bias};
      const short* bp = wq + (size_t)(col + lr) * 128 + lg * 8;
#pragma unroll
      for (int k4 = 0; k4 < 4; k4++) {
        bf16x8 bfr = *(const bf16x8*)(bp + k4 * 32);
        acc = __builtin_amdgcn_mfma_f32_16x16x32_bf16(afrag[k4], bfr, acc, 0, 0, 0);
      }
      // V frag (PV A-operand-compatible j-permuted layout)
      const int hv_ = ct >> 1;       // head
      const int dh = ct & 1;         // d half
      const int base = 8192 + (((hv_ * 2 + (w >> 1)) * 2 + dh) * 512) + lane * 8 + (w & 1) * 4;
      *(unsigned int*)(lds + base)     = pkbf(acc[0], acc[1]);
      *(unsigned int*)(lds + base + 2) = pkbf(acc[2], acc[3]);
    }
  }
  __syncthreads();
  // cooperative 1KB-per-wave coalesced chunk stores
  if (z == 0) {
#pragma unroll
    for (int kk = 0; kk < 4; kk++) {
      const int c = kk * 4 + w, hh = c & 3, tg = c >> 2;
      bf16x8 vd = *(const bf16x8*)(lds + c * 512 + lane * 8);
      *(bf16x8*)(gq + (((size_t)b_ * 4 + hh) * 32 + (n0 >> 4) + tg) * 512 + lane * 8) = vd;
    }
  } else if (z == 1) {
#pragma unroll
    for (int kk = 0; kk < 4; kk++) {
      const int c = kk * 4 + w, hh = c & 3, tg = c >> 2;
      bf16x8 vd = *(const bf16x8*)(lds + c * 512 + lane * 8);
      *(bf16x8*)(gk + (((size_t)b_ * 4 + hh) * 32 + (n0 >> 4) + tg) * 512 + lane * 8) = vd;
    }
  } else {
#pragma unroll
    for (int kk = 0; kk < 4; kk++) {
      const int c = kk * 4 + w, hh = c >> 2, ul = (c >> 1) & 1, dh = c & 1;
      bf16x8 vd = *(const bf16x8*)(lds + 8192 + c * 512 + lane * 8);
      *(bf16x8*)(gv + ((((size_t)b_ * 4 + hh) * 16 + (n0 >> 5) + ul) * 2 + dh) * 512 + lane * 8) = vd;
    }
  }
}

// ---------------- K2: fused attention (dbuf, 8 waves, 128 q-rows/block) ----------------
DEV void stage_kv8(const short* kg, const short* vg, short* buf, int T, int w, int lane) {
#pragma unroll
  for (int i = 0; i < 2; i++) {
    const int c = w * 2 + i;  // 16 chunks: 0..7 K, 8..15 V
    const short* src;
    short* dst;
    if (c < 8) {
      src = kg + ((size_t)(T * 8 + c)) * 512 + lane * 8;
      dst = buf + c * 512;
    } else {
      src = vg + ((size_t)(T * 8 + c - 8)) * 512 + lane * 8;
      dst = buf + 4096 + (c - 8) * 512;
    }
    __builtin_amdgcn_global_load_lds((const __attribute__((address_space(1))) void*)src,
                                     (__attribute__((address_space(3))) void*)dst, 16, 0, 0);
  }
}

__global__ __launch_bounds__(512, 8) void ca_attn(
    const short* __restrict__ qfrag, const short* __restrict__ kfrag,
    const short* __restrict__ vfrag, const short* __restrict__ rpbf,
    short* __restrict__ aob) {
  __shared__ short kv[2][8192];  // dbuf: K tile 8KB | V tile 8KB (per buf 16KB) = 32KB total
  const int bid = blockIdx.x;
  // XCD swizzle: the 4 qt2-blocks of one (b,h) are bid = rem + k*256 -> same XCD (256%8==0)
  const int qt2 = bid >> 8, rem = bid & 255;
  const int b_ = rem >> 2, hh = rem & 3;
  const int bh = b_ * 4 + hh;
  const int tid = threadIdx.x;
  const int w = tid >> 6, lane = tid & 63, lg = lane >> 4;
  const int qg = qt2 * 8 + w;      // one q-group (16 rows) per wave, 8 waves = 128 rows
  const int q0 = qg * 16;

  const short* kg = kfrag + (size_t)bh * 16384;
  const short* vg = vfrag + (size_t)bh * 16384;
  const bf16x8 qf = *(const bf16x8*)(qfrag + ((size_t)bh * 32 + qg) * 512 + lane * 8);
  const short* bp = rpbf + ((size_t)(hh * 32 + qg) << 13) + lane * 4;

  union PU { bf16x8 v; unsigned int u[4]; };
  PU ones;
  ones.u[0] = 0x3F803F80u; ones.u[1] = 0x3F803F80u;
  ones.u[2] = 0x3F803F80u; ones.u[3] = 0x3F803F80u;

  stage_kv8(kg, vg, &kv[0][0], 0, w, lane);
  __syncthreads();

  f32x4 o0 = {0.f, 0.f, 0.f, 0.f}, o1 = {0.f, 0.f, 0.f, 0.f}, o2 = {0.f, 0.f, 0.f, 0.f};

  for (int T = 0; T < 4; T++) {
    const int cur = T & 1;
    if (T < 3) stage_kv8(kg, vg, &kv[cur ^ 1][0], T + 1, w, lane);
    const short* kt = &kv[cur][0];
    const short* vt = &kv[cur][4096];

    u32x2 bw[8];
#pragma unroll
    for (int t = 0; t < 8; t++) bw[t] = *(const u32x2*)(bp + (size_t)(T * 8 + t) * 256);

#pragma unroll
    for (int uu = 0; uu < 4; uu++) {
      PU p;
#pragma unroll
      for (int half = 0; half < 2; half++) {
        const int t = uu * 2 + half;
        bf16x8 kf = *(const bf16x8*)(kt + t * 512 + lane * 8);
        f32x4 cin;
        cin[0] = b2f(bw[t].x << 16);
        cin[1] = b2f(bw[t].x & 0xFFFF0000u);
        cin[2] = b2f(bw[t].y << 16);
        cin[3] = b2f(bw[t].y & 0xFFFF0000u);
        f32x4 s = __builtin_amdgcn_mfma_f32_16x16x32_bf16(kf, qf, cin, 0, 0, 0);
        // no-max softmax: scores bounded (|s| < ~1), exp2 direct is exact-ratio
        p.u[half * 2 + 0] = pkbf(__builtin_exp2f(s[0]), __builtin_exp2f(s[1]));
        p.u[half * 2 + 1] = pkbf(__builtin_exp2f(s[2]), __builtin_exp2f(s[3]));
      }
      bf16x8 vf0 = *(const bf16x8*)(vt + (uu * 2 + 0) * 512 + lane * 8);
      bf16x8 vf1 = *(const bf16x8*)(vt + (uu * 2 + 1) * 512 + lane * 8);
      o0 = __builtin_amdgcn_mfma_f32_16x16x32_bf16(p.v, vf0, o0, 0, 0, 0);
      o1 = __builtin_amdgcn_mfma_f32_16x16x32_bf16(p.v, vf1, o1, 0, 0, 0);
      o2 = __builtin_amdgcn_mfma_f32_16x16x32_bf16(p.v, ones.v, o2, 0, 0, 0);
    }
    if (T < 3) __syncthreads();
  }

  // epilogue: o2[r] = row-sum for q = lg*4+r; normalize + transpose via wave-private LDS
  // last tile used kv[1]; kv[0] (16KB) is dead -> 8 waves x 1024 shorts
  short* pt = &kv[0][w * 1024];
  const int lr = lane & 15;
#pragma unroll
  for (int r = 0; r < 4; r++) {
    float iv = 1.0f / o2[r];
    pt[(lg * 4 + r) * 40 + lr] = f2b(o0[r] * iv);
    pt[(lg * 4 + r) * 40 + 16 + lr] = f2b(o1[r] * iv);
  }
  asm volatile("s_waitcnt lgkmcnt(0)" ::: "memory");
  __builtin_amdgcn_sched_barrier(0);
  {
    const int qq = lane >> 2, pp = lane & 3;
    bf16x8 od = *(const bf16x8*)(pt + qq * 40 + pp * 8);
    *(bf16x8*)(aob + ((size_t)bh * 512 + q0 + qq) * 32 + pp * 8) = od;  // 1KB/wave coalesced
  }
}

// ---------------- K3: output projection (bf16 weights, LDS-transposed stores) ----------------
__global__ __launch_bounds__(256) void ca_proj(
    const short* __restrict__ aob, const short* __restrict__ wp,
    const float* __restrict__ proj_b, float* __restrict__ out) {
  __shared__ float plds[8448];  // 4 waves x 16x132 f32
  const int t0 = blockIdx.x * 64;
  const int b_ = t0 >> 9, n0 = t0 & 511;
  const int tid = threadIdx.x;
  const int w = tid >> 6, lane = tid & 63, lr = lane & 15, lg = lane >> 4;
  bf16x8 afrag[4];
#pragma unroll
  for (int k4 = 0; k4 < 4; k4++)
    afrag[k4] = *(const bf16x8*)(aob + (((size_t)b_ * 4 + k4) * 512 + n0 + w * 16 + lr) * 32 + lg * 8);
  float* pt = plds + w * 2112;
#pragma unroll
  for (int ct = 0; ct < 8; ct++) {
    float bias = proj_b[ct * 16 + lr];
    f32x4 acc = {bias, bias, bias, bias};
    const short* bp = wp + (size_t)(ct * 16 + lr) * 128 + lg * 8;
#pragma unroll
    for (int k4 = 0; k4 < 4; k4++) {
      bf16x8 bfr = *(const bf16x8*)(bp + k4 * 32);
      acc = __builtin_amdgcn_mfma_f32_16x16x32_bf16(afrag[k4], bfr, acc, 0, 0, 0);
    }
#pragma unroll
    for (int r = 0; r < 4; r++)
      pt[(lg * 4 + r) * 132 + ct * 16 + lr] = acc[r];
  }
  asm volatile("s_waitcnt lgkmcnt(0)" ::: "memory");
  __builtin_amdgcn_sched_barrier(0);
#pragma unroll
  for (int i = 0; i < 8; i++) {
    int f = i * 256 + lane * 4;
    int row = f >> 7, col = f & 127;
    f32x4 v = *(const f32x4*)(pt + row * 132 + col);
    *(f32x4*)(out + (size_t)(t0 + w * 16) * 128 + f) = v;  // dense 1KB/wave stores
  }
}

extern "C" void kernel_launch(void* const* d_in, const int* in_sizes, int n_in,
                              void* d_out, int out_size, void* d_ws, size_t ws_size,
                              hipStream_t stream) {
  const float* x      = (const float*)d_in[0];
  const float* y      = (const float*)d_in[1];
  const float* qkv_w  = (const float*)d_in[5];
  const float* qkv_b  = (const float*)d_in[6];
  const float* proj_w = (const float*)d_in[7];
  const float* proj_b = (const float*)d_in[8];
  const float* pos_w  = (const float*)d_in[9];
  const float* pos_b  = (const float*)d_in[10];
  const float* ln1g = (const float*)d_in[11];
  const float* ln1b = (const float*)d_in[12];
  const float* p1w  = (const float*)d_in[13];
  const float* p1b  = (const float*)d_in[14];
  const float* ln2g = (const float*)d_in[15];
  const float* ln2b = (const float*)d_in[16];
  const float* p2w  = (const float*)d_in[17];
  const float* p2b  = (const float*)d_in[18];
  const float* ln3g = (const float*)d_in[19];
  const float* ln3b = (const float*)d_in[20];
  const float* p3w  = (const float*)d_in[21];
  const float* p3b  = (const float*)d_in[22];
  float* out = (float*)d_out;

  char* ws = (char*)d_ws;
  short* gq    = (short*)(ws + OFF_Q);
  short* gk    = (short*)(ws + OFF_K);
  short* gv    = (short*)(ws + OFF_V);
  short* rpbf  = (short*)(ws + OFF_RPB);
  short* aob   = (short*)(ws + OFF_AO);
  float* posb  = (float*)(ws + OFF_POS);
  short* wq    = (short*)(ws + OFF_WQ);
  short* wp    = (short*)(ws + OFF_WP);

  ca_setup<<<270, 256, 0, stream>>>(qkv_w, proj_w, wq, wp,
                                    pos_w, pos_b, ln1g, ln1b, p1w, p1b,
                                    ln2g, ln2b, p2w, p2b, ln3g, ln3b, p3w, p3b, posb);
  ca_qkv_rpb<<<2560, 256, 0, stream>>>(x, y, wq, qkv_b, gq, gk, gv, posb, rpbf);
  ca_attn<<<1024, 512, 0, stream>>>(gq, gk, gv, rpbf, aob);
  ca_proj<<<512, 256, 0, stream>>>(aob, wp, proj_b, out);
}